// Round 1
// baseline (232.696 us; speedup 1.0000x reference)
//
#include <hip/hip_runtime.h>

// DfOp: 5-tap complex FIR over first 96 freq bins of spec (8,3000,481,2);
// bins >=96 pass through. Memory-bound (~205 MB effective HBM traffic).
// v2: latency-bound fix — each thread handles TWO consecutive t rows
// (taps overlap: 6 spec loads serve 2 outputs), all 16 loads issued
// up-front into registers (prev version had VGPR_Count=20 => serialized
// loads, 29% of HBM peak). Output stores are non-temporal so the 184 MB
// of inputs stays resident in the 256 MB L3 across iterations.

#define BN    8
#define TN    3000
#define FN    481
#define NDF   96
#define NORD  5
#define ROWF  (FN * 2)       // floats per (b,t) row = 962
#define THALF (TN / 2)       // 1500 t-pairs
#define NPASS (FN - NDF)     // 385 passthrough bins

typedef float f2 __attribute__((ext_vector_type(2)));

__global__ __launch_bounds__(256) void df_kernel(const float* __restrict__ spec,
                                                 const float* __restrict__ coef,
                                                 float* __restrict__ out) {
    const int i = blockIdx.x * blockDim.x + threadIdx.x;
    const int nFiltP = BN * THALF * NDF;     // 1,152,000 filtered pair-threads
    const int nPassP = BN * THALF * NPASS;   // 4,620,000 passthrough pair-threads
    if (i >= nFiltP + nPassP) return;

    if (i < nFiltP) {
        // ---- filtered band: one thread = bin f at (t0, t0+1) ----
        const int f   = i % NDF;
        const int bth = i / NDF;
        const int th  = bth % THALF;
        const int b   = bth / THALF;
        const int t0  = th * 2;
        const long bt0   = (long)b * TN + t0;
        const long base0 = bt0 * ROWF + f * 2;       // float idx of (b,t0,f,0)

        // ---- issue ALL loads before any compute (MLP) ----
        const f2* cp = (const f2*)(coef + (bt0 * NDF + f) * (2 * NORD));
        const f2* cq = cp + NDF * NORD;              // next t row's coef
        const f2 c0a = cp[0], c0b = cp[1], c0c = cp[2], c0d = cp[3], c0e = cp[4];
        const f2 c1a = cq[0], c1b = cq[1], c1c = cq[2], c1d = cq[3], c1e = cq[4];

        const float* sp = spec + base0;
        f2 x0, x1, x2, x3, x4, x5;                   // rows t0-4 .. t0+1 at bin f
        if (t0 >= NORD - 1) {                        // fast path: 1498 of 1500 pairs
            x0 = *(const f2*)(sp - 4 * ROWF);
            x1 = *(const f2*)(sp - 3 * ROWF);
            x2 = *(const f2*)(sp - 2 * ROWF);
            x3 = *(const f2*)(sp - 1 * ROWF);
            x4 = *(const f2*)(sp);
            x5 = *(const f2*)(sp + 1 * ROWF);
        } else {                                     // t0 in {0,2}: zero-pad
            const f2 z = {0.f, 0.f};
            x0 = (t0 >= 4) ? *(const f2*)(sp - 4 * ROWF) : z;
            x1 = (t0 >= 3) ? *(const f2*)(sp - 3 * ROWF) : z;
            x2 = (t0 >= 2) ? *(const f2*)(sp - 2 * ROWF) : z;
            x3 = (t0 >= 1) ? *(const f2*)(sp - 1 * ROWF) : z;
            x4 = *(const f2*)(sp);
            x5 = *(const f2*)(sp + 1 * ROWF);
        }

        // ---- t0 output: taps x0..x4, coef c0 ----
        // cr[k] = coef[..,k], ci[k] = coef[..,5+k]
        float fr0, fi0, fr1, fi1;
        {
            const float cr0 = c0a.x, cr1 = c0a.y, cr2 = c0b.x, cr3 = c0b.y, cr4 = c0c.x;
            const float ci0 = c0c.y, ci1 = c0d.x, ci2 = c0d.y, ci3 = c0e.x, ci4 = c0e.y;
            fr0 = x0.x*cr0 - x0.y*ci0; fi0 = x0.x*ci0 + x0.y*cr0;
            fr0 += x1.x*cr1 - x1.y*ci1; fi0 += x1.x*ci1 + x1.y*cr1;
            fr0 += x2.x*cr2 - x2.y*ci2; fi0 += x2.x*ci2 + x2.y*cr2;
            fr0 += x3.x*cr3 - x3.y*ci3; fi0 += x3.x*ci3 + x3.y*cr3;
            fr0 += x4.x*cr4 - x4.y*ci4; fi0 += x4.x*ci4 + x4.y*cr4;
        }
        // ---- t0+1 output: taps x1..x5, coef c1 ----
        {
            const float cr0 = c1a.x, cr1 = c1a.y, cr2 = c1b.x, cr3 = c1b.y, cr4 = c1c.x;
            const float ci0 = c1c.y, ci1 = c1d.x, ci2 = c1d.y, ci3 = c1e.x, ci4 = c1e.y;
            fr1 = x1.x*cr0 - x1.y*ci0; fi1 = x1.x*ci0 + x1.y*cr0;
            fr1 += x2.x*cr1 - x2.y*ci1; fi1 += x2.x*ci1 + x2.y*cr1;
            fr1 += x3.x*cr2 - x3.y*ci2; fi1 += x3.x*ci2 + x3.y*cr2;
            fr1 += x4.x*cr3 - x4.y*ci3; fi1 += x4.x*ci3 + x4.y*cr3;
            fr1 += x5.x*cr4 - x5.y*ci4; fi1 += x5.x*ci4 + x5.y*cr4;
        }

        const f2 o0 = {fr0, fi0};
        const f2 o1 = {fr1, fi1};
        __builtin_nontemporal_store(o0, (f2*)(out + base0));
        __builtin_nontemporal_store(o1, (f2*)(out + base0 + ROWF));
    } else {
        // ---- passthrough band: one thread = bin fp at (t0, t0+1) ----
        const int j   = i - nFiltP;
        const int fp  = NDF + j % NPASS;
        const int bth = j / NPASS;
        const int th  = bth % THALF;
        const int b   = bth / THALF;
        const long bt0  = (long)b * TN + th * 2;
        const long idx0 = bt0 * ROWF + fp * 2;

        const f2 a = *(const f2*)(spec + idx0);
        const f2 c = *(const f2*)(spec + idx0 + ROWF);
        __builtin_nontemporal_store(a, (f2*)(out + idx0));
        __builtin_nontemporal_store(c, (f2*)(out + idx0 + ROWF));
    }
}

extern "C" void kernel_launch(void* const* d_in, const int* in_sizes, int n_in,
                              void* d_out, int out_size, void* d_ws, size_t ws_size,
                              hipStream_t stream) {
    const float* spec = (const float*)d_in[0];
    const float* coef = (const float*)d_in[1];
    float* out = (float*)d_out;

    const int nTot = BN * THALF * NDF + BN * THALF * NPASS;  // 5,772,000
    const int block = 256;
    const int grid = (nTot + block - 1) / block;
    df_kernel<<<grid, block, 0, stream>>>(spec, coef, out);
}

// Round 2
// 227.138 us; speedup vs baseline: 1.0245x; 1.0245x over previous
//
#include <hip/hip_runtime.h>

// DfOp v3: split into (A) pure streaming float4 copy spec->out and
// (B) filtered-band FIR overwrite of bins [0,96).
// Rationale: v1/v2 were stuck at 2.3 TB/s (29% HBM peak, VALU 7%) —
// bytes-in-flight-per-CU bound. Passthrough waves held only ~0.5-1 KB in
// flight; at ~900cy HBM latency that caps chip BW at ~2.5 TB/s.
// Kernel A uses the canonical 4xfloat4-per-thread copy shape (6.3 TB/s
// achievable per m13). Kernel B (18 VMEM/thread, ~128 B in flight/thread)
// re-reads the 18 MB filtered band (L3-warm from A) + streams 92 MB coef.
// Double-writing the filtered band costs ~18 MB (~3 us) and keeps A
// branch-free. Same-stream launch order guarantees B overwrites A.

#define BN    8
#define TN    3000
#define FN    481
#define NDF   96
#define NORD  5
#define ROWF  (FN * 2)       // floats per (b,t) row = 962
#define THALF (TN / 2)       // 1500 t-pairs

typedef float f2 __attribute__((ext_vector_type(2)));

// ---------------- Kernel A: flat copy ----------------
__global__ __launch_bounds__(256) void copy_kernel(const float4* __restrict__ in,
                                                   float4* __restrict__ out,
                                                   int n4) {
    const int base = blockIdx.x * (256 * 4) + threadIdx.x;
    #pragma unroll
    for (int k = 0; k < 4; ++k) {
        const int idx = base + k * 256;
        if (idx < n4) out[idx] = in[idx];
    }
}

// ---------------- Kernel B: filtered band (bins 0..95) ----------------
__global__ __launch_bounds__(256) void df_filt_kernel(const float* __restrict__ spec,
                                                      const float* __restrict__ coef,
                                                      float* __restrict__ out) {
    const int i = blockIdx.x * blockDim.x + threadIdx.x;
    const int nFiltP = BN * THALF * NDF;     // 1,152,000 pair-threads
    if (i >= nFiltP) return;

    const int f   = i % NDF;
    const int bth = i / NDF;
    const int th  = bth % THALF;
    const int b   = bth / THALF;
    const int t0  = th * 2;
    const int bt0   = b * TN + t0;
    const int base0 = bt0 * ROWF + f * 2;        // float idx of (b,t0,f,0)

    // ---- issue all loads before compute ----
    const f2* cp = (const f2*)(coef + (bt0 * NDF + f) * (2 * NORD));
    const f2* cq = cp + NDF * NORD;              // next t row's coef
    const f2 c0a = cp[0], c0b = cp[1], c0c = cp[2], c0d = cp[3], c0e = cp[4];
    const f2 c1a = cq[0], c1b = cq[1], c1c = cq[2], c1d = cq[3], c1e = cq[4];

    const float* sp = spec + base0;
    f2 x0, x1, x2, x3, x4, x5;                   // rows t0-4 .. t0+1 at bin f
    if (t0 >= NORD - 1) {                        // fast path: 1498 of 1500 pairs
        x0 = *(const f2*)(sp - 4 * ROWF);
        x1 = *(const f2*)(sp - 3 * ROWF);
        x2 = *(const f2*)(sp - 2 * ROWF);
        x3 = *(const f2*)(sp - 1 * ROWF);
        x4 = *(const f2*)(sp);
        x5 = *(const f2*)(sp + 1 * ROWF);
    } else {                                     // t0 in {0,2}: zero-pad
        const f2 z = {0.f, 0.f};
        x0 = (t0 >= 4) ? *(const f2*)(sp - 4 * ROWF) : z;
        x1 = (t0 >= 3) ? *(const f2*)(sp - 3 * ROWF) : z;
        x2 = (t0 >= 2) ? *(const f2*)(sp - 2 * ROWF) : z;
        x3 = (t0 >= 1) ? *(const f2*)(sp - 1 * ROWF) : z;
        x4 = *(const f2*)(sp);
        x5 = *(const f2*)(sp + 1 * ROWF);
    }

    float fr0, fi0, fr1, fi1;
    {   // t0 output: taps x0..x4, coef c0 (cr[k]=coef[k], ci[k]=coef[5+k])
        const float cr0 = c0a.x, cr1 = c0a.y, cr2 = c0b.x, cr3 = c0b.y, cr4 = c0c.x;
        const float ci0 = c0c.y, ci1 = c0d.x, ci2 = c0d.y, ci3 = c0e.x, ci4 = c0e.y;
        fr0 = x0.x*cr0 - x0.y*ci0; fi0 = x0.x*ci0 + x0.y*cr0;
        fr0 += x1.x*cr1 - x1.y*ci1; fi0 += x1.x*ci1 + x1.y*cr1;
        fr0 += x2.x*cr2 - x2.y*ci2; fi0 += x2.x*ci2 + x2.y*cr2;
        fr0 += x3.x*cr3 - x3.y*ci3; fi0 += x3.x*ci3 + x3.y*cr3;
        fr0 += x4.x*cr4 - x4.y*ci4; fi0 += x4.x*ci4 + x4.y*cr4;
    }
    {   // t0+1 output: taps x1..x5, coef c1
        const float cr0 = c1a.x, cr1 = c1a.y, cr2 = c1b.x, cr3 = c1b.y, cr4 = c1c.x;
        const float ci0 = c1c.y, ci1 = c1d.x, ci2 = c1d.y, ci3 = c1e.x, ci4 = c1e.y;
        fr1 = x1.x*cr0 - x1.y*ci0; fi1 = x1.x*ci0 + x1.y*cr0;
        fr1 += x2.x*cr1 - x2.y*ci1; fi1 += x2.x*ci1 + x2.y*cr1;
        fr1 += x3.x*cr2 - x3.y*ci2; fi1 += x3.x*ci2 + x3.y*cr2;
        fr1 += x4.x*cr3 - x4.y*ci3; fi1 += x4.x*ci3 + x4.y*cr3;
        fr1 += x5.x*cr4 - x5.y*ci4; fi1 += x5.x*ci4 + x5.y*cr4;
    }

    *(f2*)(out + base0)        = (f2){fr0, fi0};
    *(f2*)(out + base0 + ROWF) = (f2){fr1, fi1};
}

extern "C" void kernel_launch(void* const* d_in, const int* in_sizes, int n_in,
                              void* d_out, int out_size, void* d_ws, size_t ws_size,
                              hipStream_t stream) {
    const float* spec = (const float*)d_in[0];
    const float* coef = (const float*)d_in[1];
    float* out = (float*)d_out;

    // A: flat copy of the whole spec tensor (23,088,000 floats = 5,772,000 float4)
    const int n4 = BN * TN * FN * 2 / 4;
    const int gridA = (n4 + 1024 - 1) / 1024;
    copy_kernel<<<gridA, 256, 0, stream>>>((const float4*)spec, (float4*)out, n4);

    // B: overwrite filtered band (stream-ordered after A)
    const int nFiltP = BN * THALF * NDF;        // 1,152,000
    const int gridB = (nFiltP + 255) / 256;     // 4500
    df_filt_kernel<<<gridB, 256, 0, stream>>>(spec, coef, out);
}

// Round 4
// 226.721 us; speedup vs baseline: 1.0264x; 1.0018x over previous
//
#include <hip/hip_runtime.h>

// DfOp v4 (resubmit — round 3 was a container-acquisition infra failure,
// not a kernel result): (A) branch-free streaming copy spec->out +
// (B) filtered-band FIR.
// v3 post-mortem: copy_kernel ran at 2.49 TB/s with VGPR_Count=4 — the
// per-iteration bounds check made the compiler reuse one register pair,
// serializing load->store (1 KB/wave in flight ~= 2.5 TB/s chip-wide).
// Harness fillBuffer proves 6.6 TB/s is reachable. Fix: full blocks do 4
// unconditional float4 loads into named regs, then 4 stores; only the
// last block is guarded. B unchanged (coef-stream bound, ~3.9 TB/s).

#define BN    8
#define TN    3000
#define FN    481
#define NDF   96
#define NORD  5
#define ROWF  (FN * 2)       // floats per (b,t) row = 962
#define THALF (TN / 2)       // 1500 t-pairs

#define N4    (BN * TN * FN * 2 / 4)   // 5,772,000 float4 elements
#define CPB   1024                     // float4 per block (256 thr x 4)
#define FULLB (N4 / CPB)               // 5636 full blocks

typedef float f2 __attribute__((ext_vector_type(2)));

// ---------------- Kernel A: branch-free flat copy ----------------
__global__ __launch_bounds__(256) void copy_kernel(const float4* __restrict__ in,
                                                   float4* __restrict__ out) {
    const int base = blockIdx.x * CPB + threadIdx.x;
    if (blockIdx.x < FULLB) {
        // branch-free: 4 loads in flight, then 4 stores
        const float4 x0 = in[base];
        const float4 x1 = in[base + 256];
        const float4 x2 = in[base + 512];
        const float4 x3 = in[base + 768];
        out[base]       = x0;
        out[base + 256] = x1;
        out[base + 512] = x2;
        out[base + 768] = x3;
    } else {
        #pragma unroll
        for (int k = 0; k < 4; ++k) {
            const int idx = base + k * 256;
            if (idx < N4) out[idx] = in[idx];
        }
    }
}

// ---------------- Kernel B: filtered band (bins 0..95) ----------------
__global__ __launch_bounds__(256) void df_filt_kernel(const float* __restrict__ spec,
                                                      const float* __restrict__ coef,
                                                      float* __restrict__ out) {
    const int i = blockIdx.x * blockDim.x + threadIdx.x;
    const int nFiltP = BN * THALF * NDF;     // 1,152,000 pair-threads
    if (i >= nFiltP) return;

    const int f   = i % NDF;
    const int bth = i / NDF;
    const int th  = bth % THALF;
    const int b   = bth / THALF;
    const int t0  = th * 2;
    const int bt0   = b * TN + t0;
    const int base0 = bt0 * ROWF + f * 2;        // float idx of (b,t0,f,0)

    // ---- issue all loads before compute ----
    const f2* cp = (const f2*)(coef + (bt0 * NDF + f) * (2 * NORD));
    const f2* cq = cp + NDF * NORD;              // next t row's coef
    const f2 c0a = cp[0], c0b = cp[1], c0c = cp[2], c0d = cp[3], c0e = cp[4];
    const f2 c1a = cq[0], c1b = cq[1], c1c = cq[2], c1d = cq[3], c1e = cq[4];

    const float* sp = spec + base0;
    f2 x0, x1, x2, x3, x4, x5;                   // rows t0-4 .. t0+1 at bin f
    if (t0 >= NORD - 1) {                        // fast path: 1498 of 1500 pairs
        x0 = *(const f2*)(sp - 4 * ROWF);
        x1 = *(const f2*)(sp - 3 * ROWF);
        x2 = *(const f2*)(sp - 2 * ROWF);
        x3 = *(const f2*)(sp - 1 * ROWF);
        x4 = *(const f2*)(sp);
        x5 = *(const f2*)(sp + 1 * ROWF);
    } else {                                     // t0 in {0,2}: zero-pad
        const f2 z = {0.f, 0.f};
        x0 = (t0 >= 4) ? *(const f2*)(sp - 4 * ROWF) : z;
        x1 = (t0 >= 3) ? *(const f2*)(sp - 3 * ROWF) : z;
        x2 = (t0 >= 2) ? *(const f2*)(sp - 2 * ROWF) : z;
        x3 = (t0 >= 1) ? *(const f2*)(sp - 1 * ROWF) : z;
        x4 = *(const f2*)(sp);
        x5 = *(const f2*)(sp + 1 * ROWF);
    }

    float fr0, fi0, fr1, fi1;
    {   // t0 output: taps x0..x4, coef c0 (cr[k]=coef[k], ci[k]=coef[5+k])
        const float cr0 = c0a.x, cr1 = c0a.y, cr2 = c0b.x, cr3 = c0b.y, cr4 = c0c.x;
        const float ci0 = c0c.y, ci1 = c0d.x, ci2 = c0d.y, ci3 = c0e.x, ci4 = c0e.y;
        fr0 = x0.x*cr0 - x0.y*ci0; fi0 = x0.x*ci0 + x0.y*cr0;
        fr0 += x1.x*cr1 - x1.y*ci1; fi0 += x1.x*ci1 + x1.y*cr1;
        fr0 += x2.x*cr2 - x2.y*ci2; fi0 += x2.x*ci2 + x2.y*cr2;
        fr0 += x3.x*cr3 - x3.y*ci3; fi0 += x3.x*ci3 + x3.y*cr3;
        fr0 += x4.x*cr4 - x4.y*ci4; fi0 += x4.x*ci4 + x4.y*cr4;
    }
    {   // t0+1 output: taps x1..x5, coef c1
        const float cr0 = c1a.x, cr1 = c1a.y, cr2 = c1b.x, cr3 = c1b.y, cr4 = c1c.x;
        const float ci0 = c1c.y, ci1 = c1d.x, ci2 = c1d.y, ci3 = c1e.x, ci4 = c1e.y;
        fr1 = x1.x*cr0 - x1.y*ci0; fi1 = x1.x*ci0 + x1.y*cr0;
        fr1 += x2.x*cr1 - x2.y*ci1; fi1 += x2.x*ci1 + x2.y*cr1;
        fr1 += x3.x*cr2 - x3.y*ci2; fi1 += x3.x*ci2 + x3.y*cr2;
        fr1 += x4.x*cr3 - x4.y*ci3; fi1 += x4.x*ci3 + x4.y*cr3;
        fr1 += x5.x*cr4 - x5.y*ci4; fi1 += x5.x*ci4 + x5.y*cr4;
    }

    *(f2*)(out + base0)        = (f2){fr0, fi0};
    *(f2*)(out + base0 + ROWF) = (f2){fr1, fi1};
}

extern "C" void kernel_launch(void* const* d_in, const int* in_sizes, int n_in,
                              void* d_out, int out_size, void* d_ws, size_t ws_size,
                              hipStream_t stream) {
    const float* spec = (const float*)d_in[0];
    const float* coef = (const float*)d_in[1];
    float* out = (float*)d_out;

    // A: flat copy of the whole spec tensor, branch-free in full blocks
    const int gridA = (N4 + CPB - 1) / CPB;     // 5637
    copy_kernel<<<gridA, 256, 0, stream>>>((const float4*)spec, (float4*)out);

    // B: overwrite filtered band (stream-ordered after A)
    const int nFiltP = BN * THALF * NDF;        // 1,152,000
    const int gridB = (nFiltP + 255) / 256;     // 4500
    df_filt_kernel<<<gridB, 256, 0, stream>>>(spec, coef, out);
}